// Round 5
// baseline (71.709 us; speedup 1.0000x reference)
//
#include <hip/hip_runtime.h>
#include <math.h>

#define BB 64
#define TT 2000
#define DD 512
#define HH 256
#define KK 5
#define PP (3*KK)          // 15
#define NCH 16             // t-stripes (blocks) per batch in kernel 2
#define D4 (DD/4)          // 128
#define BPB 4              // batches per block in kernel 1
#define NB1 (BB/BPB)       // 16 blocks

// ws layout (floats):
//   [0, BB*16)                      params: [b][0..4]=m_k, [b][8..12]=inv_s_k, [b][15]=t_cut
//   [1024, 1024+BB*NCH*DD)          partials (2 MB)
//   [525312, 525312+BB)             counters (as int), zeroed by kernel 1 each call

// ---------------------------------------------------------------------------
// Kernel 1: MLP for all batches, 4 batches per block (W1 stream shared by the
// 4 teams through L1). Emits m_k, 1/s_k, t_cut per batch; zeroes the tickets.
// t_cut = max_k(m_k + 36 s_k + 1): residual mass <= K*e^-36 (~1e-15).
// ---------------------------------------------------------------------------
__global__ __launch_bounds__(1024) void mlp_params_kernel(
    const float* __restrict__ state,   // (B,1,D)
    const float* __restrict__ W1,      // (D,H) row-major
    const float* __restrict__ b1,      // (H)
    const float* __restrict__ W2,      // (H,3K) row-major
    const float* __restrict__ b2,      // (3K)
    float* __restrict__ ws_params,     // (B,16)
    int*   __restrict__ counters)      // (B)
{
    const int g    = blockIdx.x;        // batches g*4 .. g*4+3
    const int tid  = threadIdx.x;
    const int team = tid >> 8;          // 0..3  -> batch b = 4g+team
    const int wv   = (tid >> 6) & 3;    // wave within team: d-range
    const int lane = tid & 63;          // output quad: cols 4*lane..4*lane+3
    const int b    = g * BPB + team;

    __shared__ float s_state[BPB][DD];
    __shared__ float s_part[BPB][4][HH];
    __shared__ float hs[BPB][HH];
    __shared__ float s_red[BPB][16][17];
    __shared__ float pr[BPB][PP];

    for (int idx = tid; idx < BPB * DD; idx += 1024)
        s_state[idx >> 9][idx & (DD-1)] = state[(size_t)g * BPB * DD + idx];
    __syncthreads();

    // h-pre: team handles its batch; wave wv covers d in [128wv, 128wv+128)
    {
        const float4* w1v = (const float4*)W1;
        const int d0 = wv * 128;
        float4 acc = make_float4(0.f, 0.f, 0.f, 0.f);
        #pragma unroll 16
        for (int dd = 0; dd < 128; ++dd) {
            const int d    = d0 + dd;
            const float s  = s_state[team][d];
            const float4 w = w1v[(size_t)d * 64 + lane];
            acc.x += s * w.x; acc.y += s * w.y;
            acc.z += s * w.z; acc.w += s * w.w;
        }
        s_part[team][wv][4*lane+0] = acc.x;
        s_part[team][wv][4*lane+1] = acc.y;
        s_part[team][wv][4*lane+2] = acc.z;
        s_part[team][wv][4*lane+3] = acc.w;
    }
    __syncthreads();

    {
        const int col = tid & 255;       // 4 teams x 256 cols
        hs[team][col] = tanhf(b1[col] + s_part[team][0][col] + s_part[team][1][col]
                                      + s_part[team][2][col] + s_part[team][3][col]);
    }
    __syncthreads();

    // GEMV2 per team: 16 groups of 16 threads; group p computes param p (p<15)
    {
        const int loc = tid & 255;
        const int p   = loc >> 4;
        const int gg  = loc & 15;
        float a = 0.f;
        if (p < PP) {
            #pragma unroll
            for (int i = 0; i < 16; ++i)
                a += hs[team][gg + 16*i] * W2[(size_t)(gg + 16*i) * PP + p];
        }
        s_red[team][p][gg] = a;
    }
    __syncthreads();
    {
        const int loc = tid & 255;
        if (loc < PP) {
            float a = b2[loc];
            #pragma unroll
            for (int gg = 0; gg < 16; ++gg) a += s_red[team][loc][gg];
            pr[team][loc] = expf(a);
        }
    }
    __syncthreads();

    {
        const int loc = tid & 255;
        if (loc == 0) {
            float tc = 1.0f;
            #pragma unroll
            for (int k = 0; k < KK; ++k)
                tc = fmaxf(tc, pr[team][3*k] + 36.0f * pr[team][3*k+1] + 1.0f);
            ws_params[(size_t)b * 16 + 15] = tc;
            counters[b] = 0;                       // reset ticket for kernel 2
        }
        if (loc < KK) {
            ws_params[(size_t)b * 16 + loc]     = pr[team][3*loc];
            ws_params[(size_t)b * 16 + 8 + loc] = 1.0f / pr[team][3*loc + 1];
        }
    }
}

// ---------------------------------------------------------------------------
// Kernel 2: block (b,j) reduces t-stripe {j, j+NCH, ...} ∩ [0, ceil(t_cut)),
// writes its partial, takes a device-scope ticket; the last block per b sums
// the NCH partials in fixed order (deterministic) and writes context[b].
// ---------------------------------------------------------------------------
__global__ __launch_bounds__(128) void reduce_fused_kernel(
    const float* __restrict__ enc_z,    // (B,T,D)
    const float* __restrict__ ws_params,// (B,16)
    float* __restrict__ partial,        // (B,NCH,D)
    int*   __restrict__ counters,       // (B)
    float* __restrict__ out)            // (B,1,D)
{
    const int b   = blockIdx.x;
    const int j   = blockIdx.y;        // stripe
    const int tid = threadIdx.x;       // 0..127 -> float4 column

    __shared__ float pr[16];
    __shared__ float al[128];          // max nt = ceil(2000/16) = 125
    __shared__ int   ticket;

    if (tid < 16) pr[tid] = ws_params[(size_t)b * 16 + tid];
    __syncthreads();

    const int Tact = min(TT, (int)ceilf(pr[15]));
    const int nt   = (Tact - j + NCH - 1) / NCH;   // may be <= 0

    if (tid < nt) {
        const float tf = (float)(j + tid * NCH);
        float a = 0.0f;
        #pragma unroll
        for (int k = 0; k < KK; ++k) {
            const float m  = pr[k];
            const float is = pr[8 + k];
            const float hi = (tf + 0.5f - m) * is;
            const float lo = (tf - 0.5f - m) * is;
            a += 1.0f / (1.0f + expf(-hi)) - 1.0f / (1.0f + expf(-lo));
        }
        al[tid] = a;
    }
    __syncthreads();

    float ax = 0.f, ay = 0.f, az = 0.f, aw = 0.f;
    const float4* e4 = (const float4*)enc_z + (size_t)(b * TT + j) * D4 + tid;
    #pragma unroll 4
    for (int i = 0; i < nt; ++i) {
        const float a  = al[i];
        const float4 v = e4[(size_t)i * NCH * D4];
        ax += a * v.x; ay += a * v.y; az += a * v.z; aw += a * v.w;
    }
    ((float4*)partial)[(size_t)(b * NCH + j) * D4 + tid] =
        make_float4(ax, ay, az, aw);

    // make this block's partial visible device-wide, then take a ticket
    __threadfence();
    __syncthreads();
    if (tid == 0) ticket = atomicAdd(&counters[b], 1);
    __syncthreads();

    if (ticket == NCH - 1) {
        __threadfence();               // acquire: others' partials now visible
        const float* pf = partial + (size_t)b * NCH * DD + (size_t)tid * 4;
        float s0 = 0.f, s1 = 0.f, s2 = 0.f, s3 = 0.f;
        #pragma unroll
        for (int jj = 0; jj < NCH; ++jj) {
            const float* p = pf + (size_t)jj * DD;
            s0 += __hip_atomic_load(p + 0, __ATOMIC_RELAXED, __HIP_MEMORY_SCOPE_AGENT);
            s1 += __hip_atomic_load(p + 1, __ATOMIC_RELAXED, __HIP_MEMORY_SCOPE_AGENT);
            s2 += __hip_atomic_load(p + 2, __ATOMIC_RELAXED, __HIP_MEMORY_SCOPE_AGENT);
            s3 += __hip_atomic_load(p + 3, __ATOMIC_RELAXED, __HIP_MEMORY_SCOPE_AGENT);
        }
        ((float4*)out)[(size_t)b * D4 + tid] = make_float4(s0, s1, s2, s3);
    }
}

extern "C" void kernel_launch(void* const* d_in, const int* in_sizes, int n_in,
                              void* d_out, int out_size, void* d_ws, size_t ws_size,
                              hipStream_t stream) {
    const float* state = (const float*)d_in[0];
    const float* enc_z = (const float*)d_in[1];
    const float* W1    = (const float*)d_in[2];
    const float* b1    = (const float*)d_in[3];
    const float* W2    = (const float*)d_in[4];
    const float* b2    = (const float*)d_in[5];
    float* out = (float*)d_out;

    float* ws_params  = (float*)d_ws;                          // 1024 floats
    float* ws_partial = ws_params + (size_t)BB * 16;           // B*NCH*D floats
    int*   ws_count   = (int*)(ws_partial + (size_t)BB * NCH * DD);

    mlp_params_kernel<<<NB1, 1024, 0, stream>>>(state, W1, b1, W2, b2,
                                                ws_params, ws_count);
    reduce_fused_kernel<<<dim3(BB, NCH), 128, 0, stream>>>(enc_z, ws_params,
                                                           ws_partial, ws_count, out);
}

// Round 6
// 30.234 us; speedup vs baseline: 2.3718x; 2.3718x over previous
//
#include <hip/hip_runtime.h>
#include <math.h>

#define BB 64
#define TT 2000
#define DD 512
#define HH 256
#define KK 5
#define PP (3*KK)             // 15
#define TCHUNKS 40
#define TCHUNK (TT/TCHUNKS)   // 50
#define D4 (DD/4)             // 128
#define BPB 4                 // batches per block in kernel 1
#define NB1 (BB/BPB)          // 16 blocks

// ws layout (floats):
//   [0, BB*16)                      params: [b][0..4]=m_k, [b][8..12]=inv_s_k, [b][15]=t_cut
//   [1024, 1024+BB*TCHUNKS*DD)      partials (chunks with t0 < t_cut only)

// ---------------------------------------------------------------------------
// Kernel 1: MLP for all batches, 4 batches per block (the 4 teams share the
// same W1 stream through L1/L2: 8 MB total instead of 32 MB).
// t_cut = max_k(m_k + 36 s_k + 1): residual tail mass <= K*e^-36 (~1e-15).
// ---------------------------------------------------------------------------
__global__ __launch_bounds__(1024) void mlp_params_kernel(
    const float* __restrict__ state,   // (B,1,D)
    const float* __restrict__ W1,      // (D,H) row-major
    const float* __restrict__ b1,      // (H)
    const float* __restrict__ W2,      // (H,3K) row-major
    const float* __restrict__ b2,      // (3K)
    float* __restrict__ ws_params)     // (B,16)
{
    const int g    = blockIdx.x;        // batches g*4 .. g*4+3
    const int tid  = threadIdx.x;
    const int team = tid >> 8;          // 0..3  -> batch b = 4g+team
    const int wv   = (tid >> 6) & 3;    // wave within team: d-range
    const int lane = tid & 63;          // output quad: cols 4*lane..4*lane+3
    const int b    = g * BPB + team;

    __shared__ float s_state[BPB][DD];
    __shared__ float s_part[BPB][4][HH];
    __shared__ float hs[BPB][HH];
    __shared__ float s_red[BPB][16][17];
    __shared__ float pr[BPB][PP];

    for (int idx = tid; idx < BPB * DD; idx += 1024)
        s_state[idx >> 9][idx & (DD-1)] = state[(size_t)g * BPB * DD + idx];
    __syncthreads();

    // h-pre: team handles its batch; wave wv covers d in [128wv, 128wv+128)
    {
        const float4* w1v = (const float4*)W1;
        const int d0 = wv * 128;
        float4 acc = make_float4(0.f, 0.f, 0.f, 0.f);
        #pragma unroll 16
        for (int dd = 0; dd < 128; ++dd) {
            const int d    = d0 + dd;
            const float s  = s_state[team][d];
            const float4 w = w1v[(size_t)d * 64 + lane];
            acc.x += s * w.x; acc.y += s * w.y;
            acc.z += s * w.z; acc.w += s * w.w;
        }
        s_part[team][wv][4*lane+0] = acc.x;
        s_part[team][wv][4*lane+1] = acc.y;
        s_part[team][wv][4*lane+2] = acc.z;
        s_part[team][wv][4*lane+3] = acc.w;
    }
    __syncthreads();

    {
        const int col = tid & 255;       // 4 teams x 256 cols
        hs[team][col] = tanhf(b1[col] + s_part[team][0][col] + s_part[team][1][col]
                                      + s_part[team][2][col] + s_part[team][3][col]);
    }
    __syncthreads();

    // GEMV2 per team: 16 groups of 16 threads; group p computes param p (p<15)
    {
        const int loc = tid & 255;
        const int p   = loc >> 4;
        const int gg  = loc & 15;
        float a = 0.f;
        if (p < PP) {
            #pragma unroll
            for (int i = 0; i < 16; ++i)
                a += hs[team][gg + 16*i] * W2[(size_t)(gg + 16*i) * PP + p];
        }
        s_red[team][p][gg] = a;
    }
    __syncthreads();
    {
        const int loc = tid & 255;
        if (loc < PP) {
            float a = b2[loc];
            #pragma unroll
            for (int gg = 0; gg < 16; ++gg) a += s_red[team][loc][gg];
            pr[team][loc] = expf(a);
        }
    }
    __syncthreads();

    {
        const int loc = tid & 255;
        if (loc == 0) {
            float tc = 1.0f;
            #pragma unroll
            for (int k = 0; k < KK; ++k)
                tc = fmaxf(tc, pr[team][3*k] + 36.0f * pr[team][3*k+1] + 1.0f);
            ws_params[(size_t)b * 16 + 15] = tc;
        }
        if (loc < KK) {
            ws_params[(size_t)b * 16 + loc]     = pr[team][3*loc];
            ws_params[(size_t)b * 16 + 8 + loc] = 1.0f / pr[team][3*loc + 1];
        }
    }
}

// ---------------------------------------------------------------------------
// Kernel 2: partial[b,c,d] = sum_{t in chunk c} align[b,t] * enc_z[b,t,d]
// Blocks whose chunk lies entirely beyond t_cut exit without touching enc_z.
// ---------------------------------------------------------------------------
__global__ __launch_bounds__(128) void reduce_partial_kernel(
    const float* __restrict__ enc_z,    // (B,T,D)
    const float* __restrict__ ws_params,// (B,16)
    float* __restrict__ partial)        // (B,TCHUNKS,D)
{
    const int b   = blockIdx.x;
    const int c   = blockIdx.y;
    const int tid = threadIdx.x;       // 0..127 -> float4 column

    __shared__ float al[TCHUNK];
    __shared__ float pr[16];
    if (tid < 16) pr[tid] = ws_params[(size_t)b * 16 + tid];
    __syncthreads();

    const int t0 = c * TCHUNK;
    if ((float)t0 >= pr[15]) return;   // block-uniform: whole chunk is zero

    if (tid < TCHUNK) {
        const float tf = (float)(t0 + tid);
        float a = 0.0f;
        #pragma unroll
        for (int k = 0; k < KK; ++k) {
            const float m  = pr[k];
            const float is = pr[8 + k];
            const float hi = (tf + 0.5f - m) * is;
            const float lo = (tf - 0.5f - m) * is;
            a += 1.0f / (1.0f + expf(-hi)) - 1.0f / (1.0f + expf(-lo));
        }
        al[tid] = a;
    }
    __syncthreads();

    const float4* e4 = (const float4*)enc_z + (size_t)(b * TT + t0) * D4 + tid;

    float ax = 0.f, ay = 0.f, az = 0.f, aw = 0.f;
    #pragma unroll 10
    for (int t = 0; t < TCHUNK; ++t) {
        const float a  = al[t];
        const float4 v = e4[(size_t)t * D4];
        ax += a * v.x; ay += a * v.y; az += a * v.z; aw += a * v.w;
    }
    ((float4*)partial)[(size_t)(b * TCHUNKS + c) * D4 + tid] =
        make_float4(ax, ay, az, aw);
}

// ---------------------------------------------------------------------------
// Kernel 3: context[b,d] = sum over active chunks of partial[b,c,d]
// Active predicate matches kernel 2 exactly: c*TCHUNK < t_cut.
// ---------------------------------------------------------------------------
__global__ __launch_bounds__(128) void final_reduce_kernel(
    const float* __restrict__ partial,  // (B,TCHUNKS,D)
    const float* __restrict__ ws_params,// (B,16)
    float* __restrict__ out)            // (B,1,D)
{
    const int b   = blockIdx.x;
    const int tid = threadIdx.x;       // 0..127

    const float tcut = ws_params[(size_t)b * 16 + 15];
    int nc = 0;
    while (nc < TCHUNKS && (float)(nc * TCHUNK) < tcut) ++nc;

    const float4* p4 = (const float4*)partial + (size_t)b * TCHUNKS * D4 + tid;
    float4 acc = make_float4(0.f, 0.f, 0.f, 0.f);
    for (int c = 0; c < nc; ++c) {
        const float4 v = p4[(size_t)c * D4];
        acc.x += v.x; acc.y += v.y; acc.z += v.z; acc.w += v.w;
    }
    ((float4*)out)[(size_t)b * D4 + tid] = acc;
}

extern "C" void kernel_launch(void* const* d_in, const int* in_sizes, int n_in,
                              void* d_out, int out_size, void* d_ws, size_t ws_size,
                              hipStream_t stream) {
    const float* state = (const float*)d_in[0];
    const float* enc_z = (const float*)d_in[1];
    const float* W1    = (const float*)d_in[2];
    const float* b1    = (const float*)d_in[3];
    const float* W2    = (const float*)d_in[4];
    const float* b2    = (const float*)d_in[5];
    float* out = (float*)d_out;

    float* ws_params  = (float*)d_ws;                   // B*16 floats
    float* ws_partial = ws_params + (size_t)BB * 16;    // B*TCHUNKS*D floats

    mlp_params_kernel<<<NB1, 1024, 0, stream>>>(state, W1, b1, W2, b2, ws_params);
    reduce_partial_kernel<<<dim3(BB, TCHUNKS), 128, 0, stream>>>(enc_z, ws_params, ws_partial);
    final_reduce_kernel<<<BB, 128, 0, stream>>>(ws_partial, ws_params, out);
}

// Round 7
// 16.308 us; speedup vs baseline: 4.3972x; 1.8540x over previous
//
#include <hip/hip_runtime.h>
#include <math.h>

#define BB 64
#define TT 2000
#define DD 512
#define HH 256
#define KK 5
#define PP (3*KK)          // 15
#define D4 (DD/4)          // 128

// ws layout (floats):
//   [0, BB*16)   params: [b][0..4]=m_k, [b][8..12]=inv_s_k, [b][15]=t_cut

// ---------------------------------------------------------------------------
// Kernel 1 (R4's proven config): per-batch MLP. 64 blocks x 1024 threads,
// 16-way d-slice; each block reads W1 exactly once (512 KB requests/CU).
// t_cut = max_k(m_k + 36 s_k + 1): residual tail mass <= K*e^-36 (~1e-15).
// ---------------------------------------------------------------------------
__global__ __launch_bounds__(1024) void mlp_params_kernel(
    const float* __restrict__ state,   // (B,1,D)
    const float* __restrict__ W1,      // (D,H) row-major
    const float* __restrict__ b1,      // (H)
    const float* __restrict__ W2,      // (H,3K) row-major
    const float* __restrict__ b2,      // (3K)
    float* __restrict__ ws_params)     // (B,16)
{
    const int b     = blockIdx.x;
    const int tid   = threadIdx.x;
    const int q     = tid & 63;        // output quad: cols 4q..4q+3
    const int slice = tid >> 6;        // 0..15 -> d in [32*slice, 32*slice+32)

    __shared__ float s_state[DD];
    __shared__ float s_part[16][HH];
    __shared__ float hs[HH];
    __shared__ float s_red[16][17];
    __shared__ float pr[PP];

    if (tid < DD) s_state[tid] = state[(size_t)b * DD + tid];
    __syncthreads();

    // h-pre: 16-way split over d; slice's wave reads w1v[d*64+q] coalesced
    {
        const float4* w1v = (const float4*)W1;
        const int d0 = slice * 32;
        float4 acc = make_float4(0.f, 0.f, 0.f, 0.f);
        #pragma unroll 16
        for (int dd = 0; dd < 32; ++dd) {
            const int d    = d0 + dd;
            const float s  = s_state[d];
            const float4 w = w1v[(size_t)d * 64 + q];
            acc.x += s * w.x; acc.y += s * w.y;
            acc.z += s * w.z; acc.w += s * w.w;
        }
        s_part[slice][4*q+0] = acc.x;
        s_part[slice][4*q+1] = acc.y;
        s_part[slice][4*q+2] = acc.z;
        s_part[slice][4*q+3] = acc.w;
    }
    __syncthreads();

    if (tid < HH) {
        float a = b1[tid];
        #pragma unroll
        for (int s = 0; s < 16; ++s) a += s_part[s][tid];
        hs[tid] = tanhf(a);
    }
    __syncthreads();

    // params: 16 groups of 16 threads; group p computes param p (p<15)
    if (tid < 256) {
        const int p = tid >> 4;
        const int g = tid & 15;
        float a = 0.f;
        if (p < PP) {
            #pragma unroll
            for (int i = 0; i < 16; ++i)
                a += hs[g + 16*i] * W2[(size_t)(g + 16*i) * PP + p];
        }
        s_red[p][g] = a;
    }
    __syncthreads();
    if (tid < PP) {
        float a = b2[tid];
        #pragma unroll
        for (int g = 0; g < 16; ++g) a += s_red[tid][g];
        pr[tid] = expf(a);
    }
    __syncthreads();

    if (tid == 0) {
        float tc = 1.0f;
        #pragma unroll
        for (int k = 0; k < KK; ++k)
            tc = fmaxf(tc, pr[3*k] + 36.0f * pr[3*k+1] + 1.0f);
        ws_params[(size_t)b * 16 + 15] = tc;
    }
    if (tid < KK) {
        ws_params[(size_t)b * 16 + tid]     = pr[3*tid];            // mean
        ws_params[(size_t)b * 16 + 8 + tid] = 1.0f / pr[3*tid + 1]; // 1/scale
    }
}

// ---------------------------------------------------------------------------
// Kernel 2 (fused): one block per batch computes align for t < t_cut and the
// full context reduction. 512 threads = 4 t-phases x 128 float4-cols; LDS
// combine in fixed order (deterministic). No partials, no 3rd kernel, no
// fences. Active slice (~19 MB total) is L3-resident across replays.
// ---------------------------------------------------------------------------
__global__ __launch_bounds__(512) void context_kernel(
    const float* __restrict__ enc_z,    // (B,T,D)
    const float* __restrict__ ws_params,// (B,16)
    float* __restrict__ out)            // (B,1,D)
{
    const int b   = blockIdx.x;
    const int tid = threadIdx.x;
    const int h   = tid >> 7;          // t-phase 0..3
    const int col = tid & 127;         // float4 column

    __shared__ float pr[16];
    __shared__ float al[TT];
    __shared__ float s_acc[4][DD];

    if (tid < 16) pr[tid] = ws_params[(size_t)b * 16 + tid];
    __syncthreads();

    const int Tact = min(TT, (int)ceilf(pr[15]));

    for (int t = tid; t < Tact; t += 512) {
        const float tf = (float)t;
        float a = 0.0f;
        #pragma unroll
        for (int k = 0; k < KK; ++k) {
            const float m  = pr[k];
            const float is = pr[8 + k];
            const float hi = (tf + 0.5f - m) * is;
            const float lo = (tf - 0.5f - m) * is;
            a += 1.0f / (1.0f + expf(-hi)) - 1.0f / (1.0f + expf(-lo));
        }
        al[t] = a;
    }
    __syncthreads();

    // phase h accumulates t = h, h+4, h+8, ... (fixed order per thread)
    const float4* e4 = (const float4*)enc_z + (size_t)b * TT * D4 + col;
    float ax = 0.f, ay = 0.f, az = 0.f, aw = 0.f;
    #pragma unroll 4
    for (int t = h; t < Tact; t += 4) {
        const float a  = al[t];
        const float4 v = e4[(size_t)t * D4];
        ax += a * v.x; ay += a * v.y; az += a * v.z; aw += a * v.w;
    }
    s_acc[h][4*col+0] = ax;
    s_acc[h][4*col+1] = ay;
    s_acc[h][4*col+2] = az;
    s_acc[h][4*col+3] = aw;
    __syncthreads();

    // fixed-order combine of the 4 phases; threads 0..127 write the row
    if (tid < 128) {
        float4 r;
        r.x = s_acc[0][4*tid+0] + s_acc[1][4*tid+0] + s_acc[2][4*tid+0] + s_acc[3][4*tid+0];
        r.y = s_acc[0][4*tid+1] + s_acc[1][4*tid+1] + s_acc[2][4*tid+1] + s_acc[3][4*tid+1];
        r.z = s_acc[0][4*tid+2] + s_acc[1][4*tid+2] + s_acc[2][4*tid+2] + s_acc[3][4*tid+2];
        r.w = s_acc[0][4*tid+3] + s_acc[1][4*tid+3] + s_acc[2][4*tid+3] + s_acc[3][4*tid+3];
        ((float4*)out)[(size_t)b * D4 + tid] = r;
    }
}

extern "C" void kernel_launch(void* const* d_in, const int* in_sizes, int n_in,
                              void* d_out, int out_size, void* d_ws, size_t ws_size,
                              hipStream_t stream) {
    const float* state = (const float*)d_in[0];
    const float* enc_z = (const float*)d_in[1];
    const float* W1    = (const float*)d_in[2];
    const float* b1    = (const float*)d_in[3];
    const float* W2    = (const float*)d_in[4];
    const float* b2    = (const float*)d_in[5];
    float* out = (float*)d_out;

    float* ws_params = (float*)d_ws;   // B*16 floats

    mlp_params_kernel<<<BB, 1024, 0, stream>>>(state, W1, b1, W2, b2, ws_params);
    context_kernel<<<BB, 512, 0, stream>>>(enc_z, ws_params, out);
}

// Round 8
// 15.530 us; speedup vs baseline: 4.6175x; 1.0501x over previous
//
#include <hip/hip_runtime.h>
#include <math.h>

#define BB 64
#define TT 2000
#define DD 512
#define HH 256
#define KK 5
#define PP (3*KK)          // 15
#define D4 (DD/4)          // 128
#define NSL 4              // W1 d-slices (blocks per batch in kernel 1)

// ws layout (floats):
//   [0, BB*NSL*HH)   hpart: partial pre-activations, [b][slice][col]

// ---------------------------------------------------------------------------
// Kernel 1: partial h GEMV. Block (b,s) covers d in [128s, 128s+128):
// hpart[b][s][col] = sum_d state[b,d] * W1[d,col].  128 KB of W1 per block,
// 256 blocks -> every CU busy, 1/4 the per-CU L1 traffic of the 64-block k1.
// ---------------------------------------------------------------------------
__global__ __launch_bounds__(256) void h_partial_kernel(
    const float* __restrict__ state,   // (B,1,D)
    const float* __restrict__ W1,      // (D,H) row-major
    float* __restrict__ hpart)         // (B,NSL,H)
{
    const int blk = blockIdx.x;
    const int b   = blk >> 2;          // batch
    const int s   = blk & 3;           // d-slice
    const int tid = threadIdx.x;
    const int q   = tid & 63;          // col quad: cols 4q..4q+3
    const int r   = tid >> 6;          // row-group 0..3

    __shared__ float sst[128];
    __shared__ float s_part[4][HH];

    if (tid < 128) sst[tid] = state[(size_t)b * DD + s * 128 + tid];
    __syncthreads();

    const float4* w1v = (const float4*)W1;
    float4 acc = make_float4(0.f, 0.f, 0.f, 0.f);
    #pragma unroll 8
    for (int it = 0; it < 32; ++it) {
        const int dl = it * 4 + r;             // 0..127 within slice
        const int d  = s * 128 + dl;
        const float sv  = sst[dl];
        const float4 w  = w1v[(size_t)d * 64 + q];
        acc.x += sv * w.x; acc.y += sv * w.y;
        acc.z += sv * w.z; acc.w += sv * w.w;
    }
    s_part[r][4*q+0] = acc.x;
    s_part[r][4*q+1] = acc.y;
    s_part[r][4*q+2] = acc.z;
    s_part[r][4*q+3] = acc.w;
    __syncthreads();

    if (tid < HH)
        hpart[((size_t)b * NSL + s) * HH + tid] =
            s_part[0][tid] + s_part[1][tid] + s_part[2][tid] + s_part[3][tid];
}

// ---------------------------------------------------------------------------
// Kernel 2 (fused): one block per batch. Front: combine hpart -> tanh ->
// W2 GEMV -> exp -> params + t_cut (t_cut = max_k(m+36s+1), tail < K e^-36).
// Then align for t < t_cut and the context reduction, 4 t-phases x 128 cols,
// fixed-order LDS combine (deterministic). No fences, no 3rd kernel.
// ---------------------------------------------------------------------------
__global__ __launch_bounds__(512) void context_kernel(
    const float* __restrict__ enc_z,    // (B,T,D)
    const float* __restrict__ hpart,    // (B,NSL,H)
    const float* __restrict__ b1,       // (H)
    const float* __restrict__ W2,       // (H,3K)
    const float* __restrict__ b2,       // (3K)
    float* __restrict__ out)            // (B,1,D)
{
    const int b   = blockIdx.x;
    const int tid = threadIdx.x;
    const int h   = tid >> 7;          // t-phase 0..3
    const int col = tid & 127;         // float4 column

    __shared__ float hs[HH];
    __shared__ float s_red[16][17];
    __shared__ float pr[PP];
    __shared__ float prm[16];          // [k]=m_k, [8+k]=inv_s_k, [15]=t_cut
    __shared__ float al[TT];
    __shared__ float s_acc[4][DD];

    // ---- MLP tail ----
    if (tid < HH) {
        const float* hp = hpart + (size_t)b * NSL * HH + tid;
        hs[tid] = tanhf(b1[tid] + hp[0] + hp[HH] + hp[2*HH] + hp[3*HH]);
    }
    __syncthreads();

    if (tid < 256) {
        const int p = tid >> 4;
        const int g = tid & 15;
        float a = 0.f;
        if (p < PP) {
            #pragma unroll
            for (int i = 0; i < 16; ++i)
                a += hs[g + 16*i] * W2[(size_t)(g + 16*i) * PP + p];
        }
        s_red[p][g] = a;
    }
    __syncthreads();
    if (tid < PP) {
        float a = b2[tid];
        #pragma unroll
        for (int g = 0; g < 16; ++g) a += s_red[tid][g];
        pr[tid] = expf(a);
    }
    __syncthreads();
    if (tid == 0) {
        float tc = 1.0f;
        #pragma unroll
        for (int k = 0; k < KK; ++k)
            tc = fmaxf(tc, pr[3*k] + 36.0f * pr[3*k+1] + 1.0f);
        prm[15] = tc;
    }
    if (tid < KK) {
        prm[tid]     = pr[3*tid];
        prm[8 + tid] = 1.0f / pr[3*tid + 1];
    }
    __syncthreads();

    // ---- align ----
    const int Tact = min(TT, (int)ceilf(prm[15]));
    for (int t = tid; t < Tact; t += 512) {
        const float tf = (float)t;
        float a = 0.0f;
        #pragma unroll
        for (int k = 0; k < KK; ++k) {
            const float m  = prm[k];
            const float is = prm[8 + k];
            const float hi = (tf + 0.5f - m) * is;
            const float lo = (tf - 0.5f - m) * is;
            a += 1.0f / (1.0f + expf(-hi)) - 1.0f / (1.0f + expf(-lo));
        }
        al[t] = a;
    }
    __syncthreads();

    // ---- context: phase h accumulates t = h, h+4, ... (fixed per thread) ----
    const float4* e4 = (const float4*)enc_z + (size_t)b * TT * D4 + col;
    float ax = 0.f, ay = 0.f, az = 0.f, aw = 0.f;
    #pragma unroll 4
    for (int t = h; t < Tact; t += 4) {
        const float a  = al[t];
        const float4 v = e4[(size_t)t * D4];
        ax += a * v.x; ay += a * v.y; az += a * v.z; aw += a * v.w;
    }
    s_acc[h][4*col+0] = ax;
    s_acc[h][4*col+1] = ay;
    s_acc[h][4*col+2] = az;
    s_acc[h][4*col+3] = aw;
    __syncthreads();

    if (tid < 128) {
        float4 r;
        r.x = s_acc[0][4*tid+0] + s_acc[1][4*tid+0] + s_acc[2][4*tid+0] + s_acc[3][4*tid+0];
        r.y = s_acc[0][4*tid+1] + s_acc[1][4*tid+1] + s_acc[2][4*tid+1] + s_acc[3][4*tid+1];
        r.z = s_acc[0][4*tid+2] + s_acc[1][4*tid+2] + s_acc[2][4*tid+2] + s_acc[3][4*tid+2];
        r.w = s_acc[0][4*tid+3] + s_acc[1][4*tid+3] + s_acc[2][4*tid+3] + s_acc[3][4*tid+3];
        ((float4*)out)[(size_t)b * D4 + tid] = r;
    }
}

extern "C" void kernel_launch(void* const* d_in, const int* in_sizes, int n_in,
                              void* d_out, int out_size, void* d_ws, size_t ws_size,
                              hipStream_t stream) {
    const float* state = (const float*)d_in[0];
    const float* enc_z = (const float*)d_in[1];
    const float* W1    = (const float*)d_in[2];
    const float* b1    = (const float*)d_in[3];
    const float* W2    = (const float*)d_in[4];
    const float* b2    = (const float*)d_in[5];
    float* out = (float*)d_out;

    float* ws_hpart = (float*)d_ws;    // B*NSL*H floats

    h_partial_kernel<<<BB * NSL, 256, 0, stream>>>(state, W1, ws_hpart);
    context_kernel<<<BB, 512, 0, stream>>>(enc_z, ws_hpart, b1, W2, b2, out);
}

// Round 9
// 14.757 us; speedup vs baseline: 4.8595x; 1.0524x over previous
//
#include <hip/hip_runtime.h>
#include <math.h>

#define BB 64
#define TT 2000
#define DD 512
#define HH 256
#define KK 5
#define PP (3*KK)          // 15
#define D4 (DD/4)          // 128
#define NSL 4              // W1 d-slices (blocks per batch in kernel 1)
#define NJ 4               // d-column slices (blocks per batch in kernel 2)

// ws layout (floats):
//   [0, BB*NSL*HH)   hpart: partial pre-activations, [b][slice][col]

// ---------------------------------------------------------------------------
// Kernel 1 (R8, proven): partial h GEMV. Block (b,s) covers d in [128s,128s+128):
// hpart[b][s][col] = sum_d state[b,d] * W1[d,col]. 256 blocks, 128 KB W1 each.
// ---------------------------------------------------------------------------
__global__ __launch_bounds__(256) void h_partial_kernel(
    const float* __restrict__ state,   // (B,1,D)
    const float* __restrict__ W1,      // (D,H) row-major
    float* __restrict__ hpart)         // (B,NSL,H)
{
    const int blk = blockIdx.x;
    const int b   = blk >> 2;          // batch
    const int s   = blk & 3;           // d-slice
    const int tid = threadIdx.x;
    const int q   = tid & 63;          // col quad: cols 4q..4q+3
    const int r   = tid >> 6;          // row-group 0..3

    __shared__ float sst[128];
    __shared__ float s_part[4][HH];

    if (tid < 128) sst[tid] = state[(size_t)b * DD + s * 128 + tid];
    __syncthreads();

    const float4* w1v = (const float4*)W1;
    float4 acc = make_float4(0.f, 0.f, 0.f, 0.f);
    #pragma unroll 8
    for (int it = 0; it < 32; ++it) {
        const int dl = it * 4 + r;             // 0..127 within slice
        const int d  = s * 128 + dl;
        const float sv  = sst[dl];
        const float4 w  = w1v[(size_t)d * 64 + q];
        acc.x += sv * w.x; acc.y += sv * w.y;
        acc.z += sv * w.z; acc.w += sv * w.w;
    }
    s_part[r][4*q+0] = acc.x;
    s_part[r][4*q+1] = acc.y;
    s_part[r][4*q+2] = acc.z;
    s_part[r][4*q+3] = acc.w;
    __syncthreads();

    if (tid < HH)
        hpart[((size_t)b * NSL + s) * HH + tid] =
            s_part[0][tid] + s_part[1][tid] + s_part[2][tid] + s_part[3][tid];
}

// ---------------------------------------------------------------------------
// Kernel 2: block (b,j) owns output columns [128j, 128j+128). It recomputes
// the tiny MLP tail (hpart -> tanh -> W2 GEMV -> exp -> params, t_cut) and
// align locally (~20 KB reads, trivial), then streams its enc_z column slice
// for t < t_cut. 256 blocks — no cross-block reduction, no partials, no
// fences, fixed-order phase combine (deterministic).
// t_cut = max_k(m_k + 36 s_k + 1): residual tail mass <= K*e^-36.
// ---------------------------------------------------------------------------
__global__ __launch_bounds__(256) void context_kernel(
    const float* __restrict__ enc_z,    // (B,T,D)
    const float* __restrict__ hpart,    // (B,NSL,H)
    const float* __restrict__ b1,       // (H)
    const float* __restrict__ W2,       // (H,3K)
    const float* __restrict__ b2,       // (3K)
    float* __restrict__ out)            // (B,1,D)
{
    const int b   = blockIdx.x;
    const int j   = blockIdx.y;        // d-column slice 0..3
    const int tid = threadIdx.x;
    const int h   = tid >> 5;          // t-phase 0..7
    const int c   = tid & 31;          // float4 col within slice

    __shared__ float hs[HH];
    __shared__ float s_red[16][17];
    __shared__ float pr[PP];
    __shared__ float prm[16];          // [k]=m_k, [8+k]=inv_s_k, [15]=t_cut
    __shared__ float al[TT];
    __shared__ float s_acc[8][128];

    // ---- MLP tail (redundant per block; ~20 KB of L2-resident reads) ----
    {
        const float* hp = hpart + (size_t)b * NSL * HH + tid;
        hs[tid] = tanhf(b1[tid] + hp[0] + hp[HH] + hp[2*HH] + hp[3*HH]);
    }
    __syncthreads();

    {
        const int p = tid >> 4;
        const int g = tid & 15;
        float a = 0.f;
        if (p < PP) {
            #pragma unroll
            for (int i = 0; i < 16; ++i)
                a += hs[g + 16*i] * W2[(size_t)(g + 16*i) * PP + p];
        }
        s_red[p][g] = a;
    }
    __syncthreads();
    if (tid < PP) {
        float a = b2[tid];
        #pragma unroll
        for (int g = 0; g < 16; ++g) a += s_red[tid][g];
        pr[tid] = expf(a);
    }
    __syncthreads();
    if (tid == 0) {
        float tc = 1.0f;
        #pragma unroll
        for (int k = 0; k < KK; ++k)
            tc = fmaxf(tc, pr[3*k] + 36.0f * pr[3*k+1] + 1.0f);
        prm[15] = tc;
    }
    if (tid < KK) {
        prm[tid]     = pr[3*tid];
        prm[8 + tid] = 1.0f / pr[3*tid + 1];
    }
    __syncthreads();

    // ---- align for t < Tact ----
    const int Tact = min(TT, (int)ceilf(prm[15]));
    for (int t = tid; t < Tact; t += 256) {
        const float tf = (float)t;
        float a = 0.0f;
        #pragma unroll
        for (int k = 0; k < KK; ++k) {
            const float m  = prm[k];
            const float is = prm[8 + k];
            const float hi = (tf + 0.5f - m) * is;
            const float lo = (tf - 0.5f - m) * is;
            a += 1.0f / (1.0f + expf(-hi)) - 1.0f / (1.0f + expf(-lo));
        }
        al[t] = a;
    }
    __syncthreads();

    // ---- stream the (b, :, 128j..128j+128) slice; phase h: t = h, h+8, ... ----
    const float4* e4 = (const float4*)enc_z + (size_t)b * TT * D4 + j * 32 + c;
    float ax = 0.f, ay = 0.f, az = 0.f, aw = 0.f;
    #pragma unroll 4
    for (int t = h; t < Tact; t += 8) {
        const float a  = al[t];
        const float4 v = e4[(size_t)t * D4];
        ax += a * v.x; ay += a * v.y; az += a * v.z; aw += a * v.w;
    }
    s_acc[h][4*c+0] = ax;
    s_acc[h][4*c+1] = ay;
    s_acc[h][4*c+2] = az;
    s_acc[h][4*c+3] = aw;
    __syncthreads();

    // fixed-order combine of the 8 phases; threads 0..31 write the slice
    if (tid < 32) {
        float4 r = make_float4(0.f, 0.f, 0.f, 0.f);
        #pragma unroll
        for (int ph = 0; ph < 8; ++ph) {
            r.x += s_acc[ph][4*tid+0];
            r.y += s_acc[ph][4*tid+1];
            r.z += s_acc[ph][4*tid+2];
            r.w += s_acc[ph][4*tid+3];
        }
        ((float4*)out)[(size_t)b * D4 + j * 32 + tid] = r;
    }
}

extern "C" void kernel_launch(void* const* d_in, const int* in_sizes, int n_in,
                              void* d_out, int out_size, void* d_ws, size_t ws_size,
                              hipStream_t stream) {
    const float* state = (const float*)d_in[0];
    const float* enc_z = (const float*)d_in[1];
    const float* W1    = (const float*)d_in[2];
    const float* b1    = (const float*)d_in[3];
    const float* W2    = (const float*)d_in[4];
    const float* b2    = (const float*)d_in[5];
    float* out = (float*)d_out;

    float* ws_hpart = (float*)d_ws;    // B*NSL*H floats

    h_partial_kernel<<<BB * NSL, 256, 0, stream>>>(state, W1, ws_hpart);
    context_kernel<<<dim3(BB, NJ), 256, 0, stream>>>(enc_z, ws_hpart, b1, W2, b2, out);
}

// Round 10
// 13.646 us; speedup vs baseline: 5.2551x; 1.0814x over previous
//
#include <hip/hip_runtime.h>
#include <math.h>

#define BB 64
#define TT 2000
#define DD 512
#define HH 256
#define KK 5
#define PP (3*KK)          // 15
#define D4 (DD/4)          // 128
#define NJ 2               // output-column slices (blocks per batch)

// Single-kernel design: block (b,j) is fully independent.
//  1. full W1 GEMV for batch b (redundant x NJ; 512 KB W1 through L2)
//  2. tanh -> W2 GEMV -> exp -> params, t_cut   (t_cut = max_k(m+36s+1);
//     residual tail mass <= K*e^-36 ~ 1e-15, far below bf16 threshold)
//  3. align[t] for t < t_cut
//  4. stream enc_z[b, t<t_cut, 256j..256j+256), weighted-sum, write slice.
// No workspace, no fences, no atomics; all sums in fixed order -> deterministic.

__global__ __launch_bounds__(512) void molattn_fused_kernel(
    const float* __restrict__ state,   // (B,1,D)
    const float* __restrict__ enc_z,   // (B,T,D)
    const float* __restrict__ W1,      // (D,H) row-major
    const float* __restrict__ b1,      // (H)
    const float* __restrict__ W2,      // (H,3K) row-major
    const float* __restrict__ b2,      // (3K)
    float* __restrict__ out)           // (B,1,D)
{
    const int b   = blockIdx.x;
    const int j   = blockIdx.y;        // output slice: cols [256j, 256j+256)
    const int tid = threadIdx.x;

    __shared__ float s_state[DD];
    __shared__ float s_part[8][HH];    // W1-GEMV wave partials
    __shared__ float hs[HH];
    __shared__ float s_red[16][17];
    __shared__ float pr[PP];
    __shared__ float prm[16];          // [k]=m_k, [8+k]=inv_s_k, [15]=t_cut
    __shared__ float al[TT];
    __shared__ float s_acc[8][256];    // streaming phase partials

    // ---- 1. W1 GEMV: wave w covers d in [64w, 64w+64); lane q -> cols 4q..4q+3
    if (tid < DD) s_state[tid] = state[(size_t)b * DD + tid];
    __syncthreads();
    {
        const int q  = tid & 63;
        const int sl = tid >> 6;       // 0..7
        const float4* w1v = (const float4*)W1;
        const int d0 = sl * 64;
        float4 acc = make_float4(0.f, 0.f, 0.f, 0.f);
        #pragma unroll 16
        for (int dd = 0; dd < 64; ++dd) {
            const int d    = d0 + dd;
            const float s  = s_state[d];
            const float4 w = w1v[(size_t)d * 64 + q];
            acc.x += s * w.x; acc.y += s * w.y;
            acc.z += s * w.z; acc.w += s * w.w;
        }
        s_part[sl][4*q+0] = acc.x;
        s_part[sl][4*q+1] = acc.y;
        s_part[sl][4*q+2] = acc.z;
        s_part[sl][4*q+3] = acc.w;
    }
    __syncthreads();

    if (tid < HH) {
        float a = b1[tid];
        #pragma unroll
        for (int s = 0; s < 8; ++s) a += s_part[s][tid];
        hs[tid] = tanhf(a);
    }
    __syncthreads();

    // ---- 2. W2 GEMV (16 groups x 16 threads) -> exp -> params ----
    if (tid < 256) {
        const int p = tid >> 4;
        const int g = tid & 15;
        float a = 0.f;
        if (p < PP) {
            #pragma unroll
            for (int i = 0; i < 16; ++i)
                a += hs[g + 16*i] * W2[(size_t)(g + 16*i) * PP + p];
        }
        s_red[p][g] = a;
    }
    __syncthreads();
    if (tid < PP) {
        float a = b2[tid];
        #pragma unroll
        for (int g = 0; g < 16; ++g) a += s_red[tid][g];
        pr[tid] = expf(a);
    }
    __syncthreads();
    if (tid == 0) {
        float tc = 1.0f;
        #pragma unroll
        for (int k = 0; k < KK; ++k)
            tc = fmaxf(tc, pr[3*k] + 36.0f * pr[3*k+1] + 1.0f);
        prm[15] = tc;
    }
    if (tid < KK) {
        prm[tid]     = pr[3*tid];
        prm[8 + tid] = 1.0f / pr[3*tid + 1];
    }
    __syncthreads();

    // ---- 3. align for t < Tact ----
    const int Tact = min(TT, (int)ceilf(prm[15]));
    for (int t = tid; t < Tact; t += 512) {
        const float tf = (float)t;
        float a = 0.0f;
        #pragma unroll
        for (int k = 0; k < KK; ++k) {
            const float m  = prm[k];
            const float is = prm[8 + k];
            const float hi = (tf + 0.5f - m) * is;
            const float lo = (tf - 0.5f - m) * is;
            a += 1.0f / (1.0f + expf(-hi)) - 1.0f / (1.0f + expf(-lo));
        }
        al[t] = a;
    }
    __syncthreads();

    // ---- 4. stream slice: wave h handles t = h, h+8, ...; lanes c span
    // 64 consecutive float4 (1 KB contiguous per wave access). ----
    {
        const int c = tid & 63;        // float4 col within slice
        const int h = tid >> 6;        // t-phase 0..7
        const float4* e4 = (const float4*)enc_z
                         + (size_t)b * TT * D4 + j * 64 + c;
        float ax = 0.f, ay = 0.f, az = 0.f, aw = 0.f;
        #pragma unroll 4
        for (int t = h; t < Tact; t += 8) {
            const float a  = al[t];
            const float4 v = e4[(size_t)t * D4];
            ax += a * v.x; ay += a * v.y; az += a * v.z; aw += a * v.w;
        }
        s_acc[h][4*c+0] = ax;
        s_acc[h][4*c+1] = ay;
        s_acc[h][4*c+2] = az;
        s_acc[h][4*c+3] = aw;
    }
    __syncthreads();

    // fixed-order combine of the 8 phases; threads 0..63 write the slice
    if (tid < 64) {
        float4 r = make_float4(0.f, 0.f, 0.f, 0.f);
        #pragma unroll
        for (int ph = 0; ph < 8; ++ph) {
            r.x += s_acc[ph][4*tid+0];
            r.y += s_acc[ph][4*tid+1];
            r.z += s_acc[ph][4*tid+2];
            r.w += s_acc[ph][4*tid+3];
        }
        ((float4*)out)[(size_t)b * D4 + j * 64 + tid] = r;
    }
}

extern "C" void kernel_launch(void* const* d_in, const int* in_sizes, int n_in,
                              void* d_out, int out_size, void* d_ws, size_t ws_size,
                              hipStream_t stream) {
    const float* state = (const float*)d_in[0];
    const float* enc_z = (const float*)d_in[1];
    const float* W1    = (const float*)d_in[2];
    const float* b1    = (const float*)d_in[3];
    const float* W2    = (const float*)d_in[4];
    const float* b2    = (const float*)d_in[5];
    float* out = (float*)d_out;

    molattn_fused_kernel<<<dim3(BB, NJ), 512, 0, stream>>>(
        state, enc_z, W1, b1, W2, b2, out);
}

// Round 11
// 13.471 us; speedup vs baseline: 5.3233x; 1.0130x over previous
//
#include <hip/hip_runtime.h>
#include <math.h>

#define BB 64
#define TT 2000
#define DD 512
#define HH 256
#define KK 5
#define PP (3*KK)          // 15
#define D4 (DD/4)          // 128
#define NJ 2               // output-column slices (blocks per batch)
#define TAILC 14.0f        // tail cutoff: mass <= K*e^-14 ~ 4e-6, err ~2e-5 << 0.16

// Single-kernel design: block (b,j) is fully independent.
//  1. full W1 GEMV for batch b (redundant x NJ; 512 KB W1 through L2)
//  2. tanh -> W2 GEMV -> exp -> params, t_cut = max_k(m + TAILC*s + 1)
//  3. align[t] for t < t_cut
//  4. stream enc_z[b, t<t_cut, 256j..256j+256), weighted-sum, write slice.
// No workspace, no fences, no atomics; fixed-order sums -> deterministic.

__global__ __launch_bounds__(512) void molattn_fused_kernel(
    const float* __restrict__ state,   // (B,1,D)
    const float* __restrict__ enc_z,   // (B,T,D)
    const float* __restrict__ W1,      // (D,H) row-major
    const float* __restrict__ b1,      // (H)
    const float* __restrict__ W2,      // (H,3K) row-major
    const float* __restrict__ b2,      // (3K)
    float* __restrict__ out)           // (B,1,D)
{
    const int b   = blockIdx.x;
    const int j   = blockIdx.y;        // output slice: cols [256j, 256j+256)
    const int tid = threadIdx.x;

    __shared__ float s_state[DD];
    __shared__ float s_part[8][HH];    // W1-GEMV wave partials
    __shared__ float hs[HH];
    __shared__ float s_red[16][17];
    __shared__ float pr[PP];
    __shared__ float prm[16];          // [k]=m_k, [8+k]=inv_s_k, [15]=t_cut
    __shared__ float al[TT];
    __shared__ float s_acc[8][256];    // streaming phase partials

    // ---- 1. W1 GEMV: wave sl covers d in [64sl, 64sl+64); lane q -> cols 4q..4q+3
    if (tid < DD) s_state[tid] = state[(size_t)b * DD + tid];
    __syncthreads();
    {
        const int q  = tid & 63;
        const int sl = tid >> 6;       // 0..7
        const float4* w1v = (const float4*)W1;
        const int d0 = sl * 64;
        float4 acc = make_float4(0.f, 0.f, 0.f, 0.f);
        #pragma unroll 16
        for (int dd = 0; dd < 64; ++dd) {
            const int d    = d0 + dd;
            const float s  = s_state[d];
            const float4 w = w1v[(size_t)d * 64 + q];
            acc.x += s * w.x; acc.y += s * w.y;
            acc.z += s * w.z; acc.w += s * w.w;
        }
        s_part[sl][4*q+0] = acc.x;
        s_part[sl][4*q+1] = acc.y;
        s_part[sl][4*q+2] = acc.z;
        s_part[sl][4*q+3] = acc.w;
    }
    __syncthreads();

    if (tid < HH) {
        float a = b1[tid];
        #pragma unroll
        for (int s = 0; s < 8; ++s) a += s_part[s][tid];
        hs[tid] = tanhf(a);
    }
    __syncthreads();

    // ---- 2. W2 GEMV (16 groups x 16 threads) -> exp -> params ----
    if (tid < 256) {
        const int p = tid >> 4;
        const int g = tid & 15;
        float a = 0.f;
        if (p < PP) {
            #pragma unroll
            for (int i = 0; i < 16; ++i)
                a += hs[g + 16*i] * W2[(size_t)(g + 16*i) * PP + p];
        }
        s_red[p][g] = a;
    }
    __syncthreads();
    if (tid < PP) {
        float a = b2[tid];
        #pragma unroll
        for (int g = 0; g < 16; ++g) a += s_red[tid][g];
        pr[tid] = expf(a);
    }
    __syncthreads();
    if (tid == 0) {
        float tc = 1.0f;
        #pragma unroll
        for (int k = 0; k < KK; ++k)
            tc = fmaxf(tc, pr[3*k] + TAILC * pr[3*k+1] + 1.0f);
        prm[15] = tc;
    }
    if (tid < KK) {
        prm[tid]     = pr[3*tid];
        prm[8 + tid] = 1.0f / pr[3*tid + 1];
    }
    __syncthreads();

    // ---- 3. align for t < Tact ----
    const int Tact = min(TT, (int)ceilf(prm[15]));
    for (int t = tid; t < Tact; t += 512) {
        const float tf = (float)t;
        float a = 0.0f;
        #pragma unroll
        for (int k = 0; k < KK; ++k) {
            const float m  = prm[k];
            const float is = prm[8 + k];
            const float hi = (tf + 0.5f - m) * is;
            const float lo = (tf - 0.5f - m) * is;
            a += 1.0f / (1.0f + expf(-hi)) - 1.0f / (1.0f + expf(-lo));
        }
        al[t] = a;
    }
    __syncthreads();

    // ---- 4. stream slice: wave h handles t = h, h+8, ...; lanes c span
    // 64 consecutive float4 (1 KB contiguous per wave access). ----
    {
        const int c = tid & 63;        // float4 col within slice
        const int h = tid >> 6;        // t-phase 0..7
        const float4* e4 = (const float4*)enc_z
                         + (size_t)b * TT * D4 + j * 64 + c;
        float ax = 0.f, ay = 0.f, az = 0.f, aw = 0.f;
        #pragma unroll 4
        for (int t = h; t < Tact; t += 8) {
            const float a  = al[t];
            const float4 v = e4[(size_t)t * D4];
            ax += a * v.x; ay += a * v.y; az += a * v.z; aw += a * v.w;
        }
        s_acc[h][4*c+0] = ax;
        s_acc[h][4*c+1] = ay;
        s_acc[h][4*c+2] = az;
        s_acc[h][4*c+3] = aw;
    }
    __syncthreads();

    // fixed-order combine of the 8 phases; threads 0..63 write the slice
    if (tid < 64) {
        float4 r = make_float4(0.f, 0.f, 0.f, 0.f);
        #pragma unroll
        for (int ph = 0; ph < 8; ++ph) {
            r.x += s_acc[ph][4*tid+0];
            r.y += s_acc[ph][4*tid+1];
            r.z += s_acc[ph][4*tid+2];
            r.w += s_acc[ph][4*tid+3];
        }
        ((float4*)out)[(size_t)b * D4 + j * 64 + tid] = r;
    }
}

extern "C" void kernel_launch(void* const* d_in, const int* in_sizes, int n_in,
                              void* d_out, int out_size, void* d_ws, size_t ws_size,
                              hipStream_t stream) {
    const float* state = (const float*)d_in[0];
    const float* enc_z = (const float*)d_in[1];
    const float* W1    = (const float*)d_in[2];
    const float* b1    = (const float*)d_in[3];
    const float* W2    = (const float*)d_in[4];
    const float* b2    = (const float*)d_in[5];
    float* out = (float*)d_out;

    molattn_fused_kernel<<<dim3(BB, NJ), 512, 0, stream>>>(
        state, enc_z, W1, b1, W2, b2, out);
}